// Round 1
// baseline (3912.897 us; speedup 1.0000x reference)
//
#include <hip/hip_runtime.h>
#include <hip/hip_fp16.h>

#define B_   64
#define NB   128
#define E_   1024
#define DH   300
#define G3   900
#define OUTD 1924
#define WPKS 912
#define WPK_MAT (150 * WPKS)

typedef _Float16 h2raw __attribute__((ext_vector_type(2)));

__device__ __forceinline__ float dot2f(unsigned int m2, unsigned int w, float acc) {
#if __has_builtin(__builtin_amdgcn_fdot2)
    h2raw a, b;
    __builtin_memcpy(&a, &m2, 4);
    __builtin_memcpy(&b, &w, 4);
    return __builtin_amdgcn_fdot2(a, b, acc, false);
#else
    __half2 ah, bh;
    __builtin_memcpy(&ah, &m2, 4);
    __builtin_memcpy(&bh, &w, 4);
    return acc + __half2float(ah.x) * __half2float(bh.x)
               + __half2float(ah.y) * __half2float(bh.y);
#endif
}

__device__ __forceinline__ float sigmoidf_(float x) { return 1.f / (1.f + __expf(-x)); }

// ---------------- copy features into output tail ----------------
__global__ __launch_bounds__(256)
void copy_feat(const float* __restrict__ f, float* __restrict__ out) {
    const long id = (long)blockIdx.x * 256 + threadIdx.x;   // one float4 each
    const long r = id >> 8;          // row (b*128+n), 256 float4 per row
    const int  c = (int)(id & 255);
    const float4 v = ((const float4*)(f + r * E_))[c];
    ((float4*)(out + r * OUTD + 3 * DH))[c] = v;
}

// ---------------- pack recurrent weights: W(900x300) f32 -> f16 pairs [dp][o] ----------------
__global__ __launch_bounds__(256)
void pack_w(const float* __restrict__ W, unsigned int* __restrict__ dst) {
    const int id = blockIdx.x * 256 + threadIdx.x;
    if (id >= G3 * 150) return;
    const int o = id / 150;
    const int dp = id % 150;
    const float2 w = *(const float2*)(W + o * DH + 2 * dp);
    __half2 h;
    h.x = __float2half_rn(w.x);
    h.y = __float2half_rn(w.y);
    unsigned int u;
    __builtin_memcpy(&u, &h, 4);
    dst[dp * WPKS + o] = u;
}

// ---------------- fp32 tiled GEMM: C = A(MxK) * B + bias, optional relu ----------------
// BLAYOUT 0: B is (K x Nn) k-major ; BLAYOUT 1: B is (Nn x K) n-major (i.e. weight[o][k])
template<int BLAYOUT>
__global__ __launch_bounds__(256)
void gemm_bias(const float* __restrict__ A, int lda,
               const float* __restrict__ Bm, int ldb,
               const float* __restrict__ bias,
               float* __restrict__ C, int ldc,
               int M, int Nn, int K, int do_relu)
{
    __shared__ float As[16][64];
    __shared__ float Bs[16][64];
    const int tid = threadIdx.x;
    const int m0 = blockIdx.y * 64;
    const int n0 = blockIdx.x * 64;
    const int tx = tid & 15, ty = tid >> 4;
    const int ar = tid >> 2, ak = (tid & 3) << 2;
    const int bk0 = tid >> 4, bn0 = (tid & 15) << 2;
    const int bn1 = tid >> 2, bk1 = (tid & 3) << 2;

    float acc[4][4] = {{0.f}};

    for (int k0 = 0; k0 < K; k0 += 16) {
        {   // A tile (M is a multiple of 64, guard only K)
            const int gr = m0 + ar;
            const int gk = k0 + ak;
            const float* ap = A + (long)gr * lda + gk;
            float v0, v1, v2, v3;
            if (gk + 3 < K) { float4 v = *(const float4*)ap; v0 = v.x; v1 = v.y; v2 = v.z; v3 = v.w; }
            else {
                v0 = (gk + 0 < K) ? ap[0] : 0.f;
                v1 = (gk + 1 < K) ? ap[1] : 0.f;
                v2 = (gk + 2 < K) ? ap[2] : 0.f;
                v3 = (gk + 3 < K) ? ap[3] : 0.f;
            }
            As[ak + 0][ar] = v0; As[ak + 1][ar] = v1; As[ak + 2][ar] = v2; As[ak + 3][ar] = v3;
        }
        if (BLAYOUT == 0) {
            const int gk = k0 + bk0;
            const int gn = n0 + bn0;
            const float* bp = Bm + (long)gk * ldb + gn;
            float4 v;
            if (gk < K && gn + 3 < Nn) v = *(const float4*)bp;
            else {
                v.x = (gk < K && gn + 0 < Nn) ? bp[0] : 0.f;
                v.y = (gk < K && gn + 1 < Nn) ? bp[1] : 0.f;
                v.z = (gk < K && gn + 2 < Nn) ? bp[2] : 0.f;
                v.w = (gk < K && gn + 3 < Nn) ? bp[3] : 0.f;
            }
            *(float4*)&Bs[bk0][bn0] = v;
        } else {
            const int gn = n0 + bn1;
            const int gk = k0 + bk1;
            const float* bp = Bm + (long)gn * ldb + gk;
            float v0, v1, v2, v3;
            if (gn < Nn && gk + 3 < K) { float4 v = *(const float4*)bp; v0 = v.x; v1 = v.y; v2 = v.z; v3 = v.w; }
            else {
                v0 = (gn < Nn && gk + 0 < K) ? bp[0] : 0.f;
                v1 = (gn < Nn && gk + 1 < K) ? bp[1] : 0.f;
                v2 = (gn < Nn && gk + 2 < K) ? bp[2] : 0.f;
                v3 = (gn < Nn && gk + 3 < K) ? bp[3] : 0.f;
            }
            Bs[bk1 + 0][bn1] = v0; Bs[bk1 + 1][bn1] = v1; Bs[bk1 + 2][bn1] = v2; Bs[bk1 + 3][bn1] = v3;
        }
        __syncthreads();
        #pragma unroll
        for (int kk = 0; kk < 16; ++kk) {
            const float4 a4 = *(const float4*)&As[kk][ty << 2];
            const float4 b4 = *(const float4*)&Bs[kk][tx << 2];
            const float a[4] = {a4.x, a4.y, a4.z, a4.w};
            const float b[4] = {b4.x, b4.y, b4.z, b4.w};
            #pragma unroll
            for (int ii = 0; ii < 4; ++ii)
                #pragma unroll
                for (int jj = 0; jj < 4; ++jj)
                    acc[ii][jj] += a[ii] * b[jj];
        }
        __syncthreads();
    }
    const int gn0 = n0 + (tx << 2);
    #pragma unroll
    for (int ii = 0; ii < 4; ++ii) {
        const int gm = m0 + (ty << 2) + ii;
        if (gm >= M) continue;
        if (gn0 + 3 < Nn) {
            const float4 bb = *(const float4*)&bias[gn0];
            float4 o;
            o.x = acc[ii][0] + bb.x; o.y = acc[ii][1] + bb.y;
            o.z = acc[ii][2] + bb.z; o.w = acc[ii][3] + bb.w;
            if (do_relu) { o.x = fmaxf(o.x, 0.f); o.y = fmaxf(o.y, 0.f); o.z = fmaxf(o.z, 0.f); o.w = fmaxf(o.w, 0.f); }
            *(float4*)&C[(long)gm * ldc + gn0] = o;
        } else if (gn0 < Nn) {
            for (int jj = 0; jj < 4; ++jj) {
                const int gn = gn0 + jj;
                if (gn < Nn) {
                    float v = acc[ii][jj] + bias[gn];
                    if (do_relu) v = fmaxf(v, 0.f);
                    C[(long)gm * ldc + gn] = v;
                }
            }
        }
    }
}

// ---------------- xq[r] = Hl[r,:] . wq ----------------
__global__ __launch_bounds__(256)
void xq_kernel(const float* __restrict__ H, const float* __restrict__ wq, float* __restrict__ XQ) {
    const int lane = threadIdx.x & 63;
    const int wid = threadIdx.x >> 6;
    const long r = (long)blockIdx.x * 4 + wid;
    const float* h = H + r * OUTD;
    float s = 0.f;
    for (int d = lane; d < DH; d += 64) s += h[d] * wq[d];
    #pragma unroll
    for (int off = 32; off; off >>= 1) s += __shfl_xor(s, off);
    if (lane == 0) XQ[r] = s;
}

// ---------------- sequential DAG scan: one block per batch ----------------
__global__ __launch_bounds__(1024)
void scan_kernel(float* __restrict__ out,
                 const float* __restrict__ GIC,   // x@cwih.T + cbih  (B*N, 900)
                 const float* __restrict__ GHP,   // x@pwhh.T + pbhh  (B*N, 900)
                 const float* __restrict__ XQ,    // (B*N)
                 const unsigned int* __restrict__ wpk, // this layer: [2][150][912] f16-pairs
                 const float* __restrict__ cbhh,  // (900)
                 const float* __restrict__ pbih,  // (900)
                 const int* __restrict__ adj,     // (B,128,128)
                 const float* __restrict__ wk,    // (300)
                 const float* __restrict__ gatb,  // scalar
                 int l)
{
    __shared__ float Mlds[DH];
    __shared__ unsigned int M2[152];
    __shared__ float wsm[NB];
    __shared__ float betas[NB];
    __shared__ float red[16];
    __shared__ float ghc[G3];
    __shared__ float gip[G3];

    const int tid = threadIdx.x;
    const int lane = tid & 63;
    const int wid = tid >> 6;
    const int b = blockIdx.x;
    const float bg = *gatb;

    float* outb = out + (long)b * NB * OUTD;
    const float* xcol = outb + l * DH;        // Hl rows
    float* ycol = outb + (l + 1) * DH;        // H_{l+1} rows = scan buf
    const float* gicb = GIC + (long)b * NB * G3;
    const float* ghpb = GHP + (long)b * NB * G3;
    const int* adjb = adj + b * NB * NB;

    for (int i = 0; i < NB; ++i) {
        // ---- Phase A+B: softmax weights and M (M=0 at i=0) ----
        if (i == 0) {
            if (tid < DH) Mlds[tid] = 0.f;
            if (tid < 152) M2[tid] = 0u;
        } else {
            float aj = -3.0e38f;
            bool valid = false;
            if (tid < i) {
                valid = (adjb[i * NB + tid] != 0);
                if (valid) aj = XQ[b * NB + i] + bg + betas[tid];
            }
            if (tid < NB) {
                float mx = aj;
                #pragma unroll
                for (int off = 32; off; off >>= 1) mx = fmaxf(mx, __shfl_xor(mx, off));
                if (lane == 0) red[wid] = mx;
            }
            __syncthreads();
            const float amax = fmaxf(red[0], red[1]);
            float e = 0.f;
            if (tid < NB) {
                e = valid ? __expf(aj - amax) : 0.f;
                float s = e;
                #pragma unroll
                for (int off = 32; off; off >>= 1) s += __shfl_xor(s, off);
                if (lane == 0) red[8 + wid] = s;
            }
            __syncthreads();
            const float denom = red[8] + red[9];
            if (tid < NB) wsm[tid] = e / denom;
            __syncthreads();
            if (tid < DH) {          // M[d] = sum_j w_j * buf[j][d]
                float m = 0.f;
                const float* brow = ycol + tid;
                for (int j = 0; j < i; ++j)
                    m += wsm[j] * brow[(long)j * OUTD];
                Mlds[tid] = m;
            }
            __syncthreads();
            if (tid < 150) {
                __half2 h;
                h.x = __float2half_rn(Mlds[2 * tid]);
                h.y = __float2half_rn(Mlds[2 * tid + 1]);
                unsigned int u;
                __builtin_memcpy(&u, &h, 4);
                M2[tid] = u;
            }
        }
        __syncthreads();
        // ---- Phase C: matvecs gh_c = M@cwhh.T (mat0), gi_p = M@pwih.T (mat1) ----
        if (tid < 450) {
            const int mat = tid / 225;
            const int tt = tid % 225;             // 4 outputs per thread
            const unsigned int* wm = wpk + mat * WPK_MAT + (tt << 2);
            float a0 = 0.f, a1 = 0.f, a2 = 0.f, a3 = 0.f;
            for (int dp = 0; dp < 150; ++dp) {
                const unsigned int m2 = M2[dp];
                const uint4 w = *(const uint4*)(wm + dp * WPKS);
                a0 = dot2f(m2, w.x, a0);
                a1 = dot2f(m2, w.y, a1);
                a2 = dot2f(m2, w.z, a2);
                a3 = dot2f(m2, w.w, a3);
            }
            float* dst = (mat == 0) ? ghc : gip;
            *(float4*)&dst[tt << 2] = make_float4(a0, a1, a2, a3);
        }
        __syncthreads();
        // ---- Phase D: gates + write new row ----
        float rowv = 0.f;
        if (tid < DH) {
            const int d = tid;
            const float* gic = gicb + (long)i * G3;
            const float* ghp = ghpb + (long)i * G3;
            const float xi = xcol[(long)i * OUTD + d];
            const float Mi = Mlds[d];
            const float hc0 = ghc[d] + cbhh[d];
            const float hc1 = ghc[DH + d] + cbhh[DH + d];
            const float hc2 = ghc[2 * DH + d] + cbhh[2 * DH + d];
            const float rc = sigmoidf_(gic[d] + hc0);
            const float zc = sigmoidf_(gic[DH + d] + hc1);
            const float nc = tanhf(gic[2 * DH + d] + rc * hc2);
            const float Cc = (1.f - zc) * nc + zc * Mi;
            const float ip0 = gip[d] + pbih[d];
            const float ip1 = gip[DH + d] + pbih[DH + d];
            const float ip2 = gip[2 * DH + d] + pbih[2 * DH + d];
            const float rp = sigmoidf_(ip0 + ghp[d]);
            const float zp = sigmoidf_(ip1 + ghp[DH + d]);
            const float np = tanhf(ip2 + rp * ghp[2 * DH + d]);
            const float Pp = (1.f - zp) * np + zp * xi;
            rowv = Cc + Pp;
            ycol[(long)i * OUTD + d] = rowv;
        }
        // ---- Phase E: beta[i] = row . wk ----
        float v = 0.f;
        if (tid < DH) v = rowv * wk[tid];
        if (wid < 5) {
            #pragma unroll
            for (int off = 32; off; off >>= 1) v += __shfl_xor(v, off);
            if (lane == 0) red[wid] = v;
        }
        __syncthreads();
        if (tid == 0) betas[i] = red[0] + red[1] + red[2] + red[3] + red[4];
        __syncthreads();
    }
}

extern "C" void kernel_launch(void* const* d_in, const int* in_sizes, int n_in,
                              void* d_out, int out_size, void* d_ws, size_t ws_size,
                              hipStream_t stream) {
    (void)in_sizes; (void)n_in; (void)out_size; (void)ws_size;
    const float* features = (const float*)d_in[0];
    const float* fc1_w    = (const float*)d_in[1];
    const float* fc1_b    = (const float*)d_in[2];
    const float* gat_w    = (const float*)d_in[3];
    const float* gat_b    = (const float*)d_in[4];
    const float* gc_wih   = (const float*)d_in[5];
    const float* gc_whh   = (const float*)d_in[6];
    const float* gc_bih   = (const float*)d_in[7];
    const float* gc_bhh   = (const float*)d_in[8];
    const float* gp_wih   = (const float*)d_in[9];
    const float* gp_whh   = (const float*)d_in[10];
    const float* gp_bih   = (const float*)d_in[11];
    const float* gp_bhh   = (const float*)d_in[12];
    const int*   adj      = (const int*)d_in[13];
    float* out = (float*)d_out;

    float* GIC = (float*)d_ws;                       // 64*128*900
    float* GHP = GIC + (long)B_ * NB * G3;           // 64*128*900
    float* XQ  = GHP + (long)B_ * NB * G3;           // 8192
    unsigned int* WPK = (unsigned int*)(XQ + (long)B_ * NB);  // 4 * 150 * 912

    // features tail copy
    copy_feat<<<dim3((B_ * NB * E_) / 1024), 256, 0, stream>>>(features, out);

    // pack recurrent weights (gc_whh, gp_wih per layer) to f16-pair layout
    pack_w<<<dim3(528), 256, 0, stream>>>(gc_whh,            WPK + 0 * WPK_MAT);
    pack_w<<<dim3(528), 256, 0, stream>>>(gp_wih,            WPK + 1 * WPK_MAT);
    pack_w<<<dim3(528), 256, 0, stream>>>(gc_whh + G3 * DH,  WPK + 2 * WPK_MAT);
    pack_w<<<dim3(528), 256, 0, stream>>>(gp_wih + G3 * DH,  WPK + 3 * WPK_MAT);

    // H0 = relu(features @ fc1_w + fc1_b) -> out cols [0,300)
    gemm_bias<0><<<dim3(5, 128), 256, 0, stream>>>(
        features, E_, fc1_w, DH, fc1_b, out, OUTD, B_ * NB, DH, E_, 1);

    for (int l = 0; l < 2; ++l) {
        const float* Hl = out + l * DH;
        // GI_C = Hl @ cwih.T + cbih ; GH_P = Hl @ pwhh.T + pbhh
        gemm_bias<1><<<dim3(15, 128), 256, 0, stream>>>(
            Hl, OUTD, gc_wih + l * G3 * DH, DH, gc_bih + l * G3, GIC, G3, B_ * NB, G3, DH, 0);
        gemm_bias<1><<<dim3(15, 128), 256, 0, stream>>>(
            Hl, OUTD, gp_whh + l * G3 * DH, DH, gp_bhh + l * G3, GHP, G3, B_ * NB, G3, DH, 0);
        xq_kernel<<<dim3(B_ * NB / 4), 256, 0, stream>>>(Hl, gat_w + l * 2 * DH, XQ);
        scan_kernel<<<dim3(B_), 1024, 0, stream>>>(
            out, GIC, GHP, XQ, WPK + l * 2 * WPK_MAT,
            gc_bhh + l * G3, gp_bih + l * G3, adj,
            gat_w + l * 2 * DH + DH, gat_b + l, l);
    }
}

// Round 2
// 2587.755 us; speedup vs baseline: 1.5121x; 1.5121x over previous
//
#include <hip/hip_runtime.h>
#include <hip/hip_fp16.h>

#define B_   64
#define NB   128
#define E_   1024
#define DH   300
#define G3   900
#define OUTD 1924
#define SLICES 4
#define SLICE_D 75
#define ROWS_PB 450   // 6*75 weight rows per slice block
#define PK_STRIDE 1800

typedef _Float16 h2raw __attribute__((ext_vector_type(2)));

__device__ __forceinline__ float dot2f(unsigned int m2, unsigned int w, float acc) {
    h2raw a, b;
    __builtin_memcpy(&a, &m2, 4);
    __builtin_memcpy(&b, &w, 4);
    return __builtin_amdgcn_fdot2(a, b, acc, false);
}

__device__ __forceinline__ float sigmoidf_(float x) { return 1.f / (1.f + __expf(-x)); }
__device__ __forceinline__ float tanh_fast(float x) { return 1.f - 2.f / (__expf(2.f * x) + 1.f); }

// ---------------- copy features into output tail ----------------
__global__ __launch_bounds__(256)
void copy_feat(const float* __restrict__ f, float* __restrict__ out) {
    const long id = (long)blockIdx.x * 256 + threadIdx.x;   // one float4 each
    const long r = id >> 8;          // row (b*128+n), 256 float4 per row
    const int  c = (int)(id & 255);
    const float4 v = ((const float4*)(f + r * E_))[c];
    ((float4*)(out + r * OUTD + 3 * DH))[c] = v;
}

// ---------------- pack recurrent weights -> PK2[l][kp(150)][R(1800)] f16-pairs ----------------
// R = mat*900 + o ; mat0 = gc_whh (gh_c), mat1 = gp_wih (gi_p); value = (W[o][2kp], W[o][2kp+1])
__global__ __launch_bounds__(256)
void pack2(const float* __restrict__ gc_whh, const float* __restrict__ gp_wih,
           unsigned int* __restrict__ dst) {
    const int id = blockIdx.x * 256 + threadIdx.x;
    if (id >= 2 * 150 * PK_STRIDE) return;
    const int l   = id / (150 * PK_STRIDE);
    const int rem = id % (150 * PK_STRIDE);
    const int kp  = rem / PK_STRIDE;
    const int R   = rem % PK_STRIDE;
    const int mat = R / G3;
    const int o   = R % G3;
    const float* W = (mat ? gp_wih : gc_whh) + (long)l * G3 * DH;
    const float2 v = *(const float2*)(W + (long)o * DH + 2 * kp);
    __half2 h;
    h.x = __float2half_rn(v.x);
    h.y = __float2half_rn(v.y);
    unsigned int u;
    __builtin_memcpy(&u, &h, 4);
    dst[id] = u;
}

// ---------------- fp32 tiled GEMM: C = A(MxK) * B + bias, optional relu ----------------
template<int BLAYOUT>
__global__ __launch_bounds__(256)
void gemm_bias(const float* __restrict__ A, int lda,
               const float* __restrict__ Bm, int ldb,
               const float* __restrict__ bias,
               float* __restrict__ C, int ldc,
               int M, int Nn, int K, int do_relu)
{
    __shared__ float As[16][64];
    __shared__ float Bs[16][64];
    const int tid = threadIdx.x;
    const int m0 = blockIdx.y * 64;
    const int n0 = blockIdx.x * 64;
    const int tx = tid & 15, ty = tid >> 4;
    const int ar = tid >> 2, ak = (tid & 3) << 2;
    const int bk0 = tid >> 4, bn0 = (tid & 15) << 2;
    const int bn1 = tid >> 2, bk1 = (tid & 3) << 2;

    float acc[4][4] = {{0.f}};

    for (int k0 = 0; k0 < K; k0 += 16) {
        {
            const int gr = m0 + ar;
            const int gk = k0 + ak;
            const float* ap = A + (long)gr * lda + gk;
            float v0, v1, v2, v3;
            if (gk + 3 < K) { float4 v = *(const float4*)ap; v0 = v.x; v1 = v.y; v2 = v.z; v3 = v.w; }
            else {
                v0 = (gk + 0 < K) ? ap[0] : 0.f;
                v1 = (gk + 1 < K) ? ap[1] : 0.f;
                v2 = (gk + 2 < K) ? ap[2] : 0.f;
                v3 = (gk + 3 < K) ? ap[3] : 0.f;
            }
            As[ak + 0][ar] = v0; As[ak + 1][ar] = v1; As[ak + 2][ar] = v2; As[ak + 3][ar] = v3;
        }
        if (BLAYOUT == 0) {
            const int gk = k0 + bk0;
            const int gn = n0 + bn0;
            const float* bp = Bm + (long)gk * ldb + gn;
            float4 v;
            if (gk < K && gn + 3 < Nn) v = *(const float4*)bp;
            else {
                v.x = (gk < K && gn + 0 < Nn) ? bp[0] : 0.f;
                v.y = (gk < K && gn + 1 < Nn) ? bp[1] : 0.f;
                v.z = (gk < K && gn + 2 < Nn) ? bp[2] : 0.f;
                v.w = (gk < K && gn + 3 < Nn) ? bp[3] : 0.f;
            }
            *(float4*)&Bs[bk0][bn0] = v;
        } else {
            const int gn = n0 + bn1;
            const int gk = k0 + bk1;
            const float* bp = Bm + (long)gn * ldb + gk;
            float v0, v1, v2, v3;
            if (gn < Nn && gk + 3 < K) { float4 v = *(const float4*)bp; v0 = v.x; v1 = v.y; v2 = v.z; v3 = v.w; }
            else {
                v0 = (gn < Nn && gk + 0 < K) ? bp[0] : 0.f;
                v1 = (gn < Nn && gk + 1 < K) ? bp[1] : 0.f;
                v2 = (gn < Nn && gk + 2 < K) ? bp[2] : 0.f;
                v3 = (gn < Nn && gk + 3 < K) ? bp[3] : 0.f;
            }
            Bs[bk1 + 0][bn1] = v0; Bs[bk1 + 1][bn1] = v1; Bs[bk1 + 2][bn1] = v2; Bs[bk1 + 3][bn1] = v3;
        }
        __syncthreads();
        #pragma unroll
        for (int kk = 0; kk < 16; ++kk) {
            const float4 a4 = *(const float4*)&As[kk][ty << 2];
            const float4 b4 = *(const float4*)&Bs[kk][tx << 2];
            const float a[4] = {a4.x, a4.y, a4.z, a4.w};
            const float b[4] = {b4.x, b4.y, b4.z, b4.w};
            #pragma unroll
            for (int ii = 0; ii < 4; ++ii)
                #pragma unroll
                for (int jj = 0; jj < 4; ++jj)
                    acc[ii][jj] += a[ii] * b[jj];
        }
        __syncthreads();
    }
    const int gn0 = n0 + (tx << 2);
    #pragma unroll
    for (int ii = 0; ii < 4; ++ii) {
        const int gm = m0 + (ty << 2) + ii;
        if (gm >= M) continue;
        if (gn0 + 3 < Nn) {
            const float4 bb = *(const float4*)&bias[gn0];
            float4 o;
            o.x = acc[ii][0] + bb.x; o.y = acc[ii][1] + bb.y;
            o.z = acc[ii][2] + bb.z; o.w = acc[ii][3] + bb.w;
            if (do_relu) { o.x = fmaxf(o.x, 0.f); o.y = fmaxf(o.y, 0.f); o.z = fmaxf(o.z, 0.f); o.w = fmaxf(o.w, 0.f); }
            *(float4*)&C[(long)gm * ldc + gn0] = o;
        } else if (gn0 < Nn) {
            for (int jj = 0; jj < 4; ++jj) {
                const int gn = gn0 + jj;
                if (gn < Nn) {
                    float v = acc[ii][jj] + bias[gn];
                    if (do_relu) v = fmaxf(v, 0.f);
                    C[(long)gm * ldc + gn] = v;
                }
            }
        }
    }
}

// ---------------- xq[r] = Hl[r,:] . wq ----------------
__global__ __launch_bounds__(256)
void xq_kernel(const float* __restrict__ H, const float* __restrict__ wq, float* __restrict__ XQ) {
    const int lane = threadIdx.x & 63;
    const int wid = threadIdx.x >> 6;
    const long r = (long)blockIdx.x * 4 + wid;
    const float* h = H + r * OUTD;
    float s = 0.f;
    for (int d = lane; d < DH; d += 64) s += h[d] * wq[d];
    #pragma unroll
    for (int off = 32; off; off >>= 1) s += __shfl_xor(s, off);
    if (lane == 0) XQ[r] = s;
}

// ---------------- DAG scan: 4 slice-blocks per batch, weights in registers ----------------
// dynamic LDS: f16-pair y-history [128][152] uints (77824 B)
__global__ __launch_bounds__(512, 2)
void scan2(float* __restrict__ out,
           const float* __restrict__ GIC,
           const float* __restrict__ GHP,
           const float* __restrict__ XQ,
           const unsigned int* __restrict__ PK2L,  // layer base [150][1800]
           const float* __restrict__ cbhh,
           const float* __restrict__ pbih,
           const int* __restrict__ adj,
           const float* __restrict__ wk,
           const float* __restrict__ gatb,
           float* __restrict__ PB,
           unsigned int* __restrict__ FLG,
           int l)
{
    extern __shared__ unsigned int histp[];   // [128][152]
    __shared__ float wsm[NB];
    __shared__ float betas[NB];
    __shared__ float xqs[NB];
    __shared__ float Mlds[DH];
    __shared__ __align__(16) unsigned int M2[152];
    __shared__ float gmv[ROWS_PB];
    __shared__ float red[8];
    __shared__ float red2[8];

    const int tid = threadIdx.x;
    const int lane = tid & 63;
    const int wid = tid >> 6;
    const int b = blockIdx.x & 63;
    const int k = blockIdx.x >> 6;     // slice id; blocks b, b+64, b+128, b+192 share a batch

    const float bg = *gatb;
    float* outb = out + (long)b * NB * OUTD;
    const float* xcol = outb + l * DH;
    float* ycol = outb + (l + 1) * DH;
    const float* gicb = GIC + (long)b * NB * G3;
    const float* ghpb = GHP + (long)b * NB * G3;
    const int* adjb = adj + b * NB * NB;
    float* pb = PB + (long)b * NB * 4;
    unsigned int* flg = FLG + b * NB;

    if (tid < NB) xqs[tid] = XQ[b * NB + tid];
    if (tid >= 150 && tid < 152) M2[tid] = 0u;

    // ---- load this slice's weight rows into registers ----
    int R;
    {
        const int t = (tid < ROWS_PB) ? tid : 0;
        const int d = t % SLICE_D;
        const int r = t / SLICE_D;            // 0..5 = (mat, gate)
        const int mat = r / 3, gate = r % 3;
        R = mat * G3 + gate * DH + k * SLICE_D + d;
    }
    unsigned int w[152];
    #pragma unroll
    for (int j = 0; j < 150; ++j) w[j] = PK2L[j * PK_STRIDE + R];
    w[150] = 0u; w[151] = 0u;

    __syncthreads();

    for (int i = 0; i < NB; ++i) {
        if (i > 0) {
            // ---- wait for all 4 slices of row i-1 (release/acquire via flag) ----
            if (tid == 0) {
                while (__hip_atomic_load(&flg[i - 1], __ATOMIC_RELAXED, __HIP_MEMORY_SCOPE_AGENT) < 4u)
                    __builtin_amdgcn_s_sleep(1);
                (void)__hip_atomic_load(&flg[i - 1], __ATOMIC_ACQUIRE, __HIP_MEMORY_SCOPE_AGENT);
                const float4 p = *(const float4*)&pb[(i - 1) * 4];
                betas[i - 1] = p.x + p.y + p.z + p.w;
            }
            __syncthreads();

            // ---- stash row i-1 into f16 LDS history (overlaps with softmax) ----
            if (tid < 150) {
                const float2 v = *(const float2*)(ycol + (long)(i - 1) * OUTD + 2 * tid);
                __half2 h;
                h.x = __float2half_rn(v.x);
                h.y = __float2half_rn(v.y);
                unsigned int u;
                __builtin_memcpy(&u, &h, 4);
                histp[(i - 1) * 152 + tid] = u;
            }

            // ---- softmax over predecessors j < i ----
            float aj = -3.0e38f;
            bool valid = false;
            if (tid < i) {
                valid = (adjb[i * NB + tid] != 0);
                if (valid) aj = xqs[i] + bg + betas[tid];
            }
            float mx = aj;
            #pragma unroll
            for (int off = 32; off; off >>= 1) mx = fmaxf(mx, __shfl_xor(mx, off));
            if (lane == 0) red[wid] = mx;
            __syncthreads();
            float amax = red[0];
            #pragma unroll
            for (int q = 1; q < 8; ++q) amax = fmaxf(amax, red[q]);
            const float e = valid ? __expf(aj - amax) : 0.f;
            float s = e;
            #pragma unroll
            for (int off = 32; off; off >>= 1) s += __shfl_xor(s, off);
            if (lane == 0) red2[wid] = s;
            __syncthreads();
            float denom = red2[0];
            #pragma unroll
            for (int q = 1; q < 8; ++q) denom += red2[q];
            if (tid < NB) wsm[tid] = e / denom;
            __syncthreads();

            // ---- M = sum_j w_j * y_j  (from LDS history; 150 threads, 2 dims each) ----
            if (tid < 150) {
                float m0 = 0.f, m1 = 0.f;
                #pragma unroll 4
                for (int j = 0; j < i; ++j) {
                    const unsigned int u = histp[j * 152 + tid];
                    __half2 h;
                    __builtin_memcpy(&h, &u, 4);
                    const float wj = wsm[j];
                    m0 = fmaf(wj, __half2float(h.x), m0);
                    m1 = fmaf(wj, __half2float(h.y), m1);
                }
                Mlds[2 * tid] = m0;
                Mlds[2 * tid + 1] = m1;
                __half2 h;
                h.x = __float2half_rn(m0);
                h.y = __float2half_rn(m1);
                unsigned int u;
                __builtin_memcpy(&u, &h, 4);
                M2[tid] = u;
            }
        } else {
            if (tid < DH) Mlds[tid] = 0.f;
            if (tid < 150) M2[tid] = 0u;
        }
        __syncthreads();

        // ---- matvec from register weights: 450 rows, one per thread ----
        if (tid < ROWS_PB) {
            float a0 = 0.f, a1 = 0.f;
            #pragma unroll
            for (int j4 = 0; j4 < 152; j4 += 4) {
                const uint4 m4 = *(const uint4*)&M2[j4];
                a0 = dot2f(m4.x, w[j4 + 0], a0);
                a1 = dot2f(m4.y, w[j4 + 1], a1);
                a0 = dot2f(m4.z, w[j4 + 2], a0);
                a1 = dot2f(m4.w, w[j4 + 3], a1);
            }
            gmv[tid] = a0 + a1;
        }
        __syncthreads();

        // ---- gates for this slice's 75 dims ----
        float bv = 0.f;
        if (tid < SLICE_D) {
            const int D = k * SLICE_D + tid;
            const float* gic = gicb + (long)i * G3;
            const float* ghp = ghpb + (long)i * G3;
            const float xi = xcol[(long)i * OUTD + D];
            const float Mi = Mlds[D];
            const float hc0 = gmv[0 * SLICE_D + tid] + cbhh[D];
            const float hc1 = gmv[1 * SLICE_D + tid] + cbhh[DH + D];
            const float hc2 = gmv[2 * SLICE_D + tid] + cbhh[2 * DH + D];
            const float rc = sigmoidf_(gic[D] + hc0);
            const float zc = sigmoidf_(gic[DH + D] + hc1);
            const float nc = tanh_fast(gic[2 * DH + D] + rc * hc2);
            const float Cc = (1.f - zc) * nc + zc * Mi;
            const float ip0 = gmv[3 * SLICE_D + tid] + pbih[D];
            const float ip1 = gmv[4 * SLICE_D + tid] + pbih[DH + D];
            const float ip2 = gmv[5 * SLICE_D + tid] + pbih[2 * DH + D];
            const float rp = sigmoidf_(ip0 + ghp[D]);
            const float zp = sigmoidf_(ip1 + ghp[DH + D]);
            const float np = tanh_fast(ip2 + rp * ghp[2 * DH + D]);
            const float Pp = (1.f - zp) * np + zp * xi;
            const float rowv = Cc + Pp;
            ycol[(long)i * OUTD + D] = rowv;
            bv = rowv * wk[D];
        }
        // partial beta: reduce over waves 0..1 (others contribute 0)
        #pragma unroll
        for (int off = 32; off; off >>= 1) bv += __shfl_xor(bv, off);
        if (lane == 0) red[wid] = bv;
        __syncthreads();

        if (tid == 0) {
            pb[i * 4 + k] = red[0] + red[1];
            __hip_atomic_fetch_add(&flg[i], 1u, __ATOMIC_RELEASE, __HIP_MEMORY_SCOPE_AGENT);
        }
        __syncthreads();
    }
}

extern "C" void kernel_launch(void* const* d_in, const int* in_sizes, int n_in,
                              void* d_out, int out_size, void* d_ws, size_t ws_size,
                              hipStream_t stream) {
    (void)in_sizes; (void)n_in; (void)out_size; (void)ws_size;
    const float* features = (const float*)d_in[0];
    const float* fc1_w    = (const float*)d_in[1];
    const float* fc1_b    = (const float*)d_in[2];
    const float* gat_w    = (const float*)d_in[3];
    const float* gat_b    = (const float*)d_in[4];
    const float* gc_wih   = (const float*)d_in[5];
    const float* gc_whh   = (const float*)d_in[6];
    const float* gc_bih   = (const float*)d_in[7];
    const float* gc_bhh   = (const float*)d_in[8];
    const float* gp_wih   = (const float*)d_in[9];
    const float* gp_whh   = (const float*)d_in[10];
    const float* gp_bih   = (const float*)d_in[11];
    const float* gp_bhh   = (const float*)d_in[12];
    const int*   adj      = (const int*)d_in[13];
    float* out = (float*)d_out;

    float* GIC = (float*)d_ws;                            // 64*128*900
    float* GHP = GIC + (long)B_ * NB * G3;                // 64*128*900
    float* XQ  = GHP + (long)B_ * NB * G3;                // 8192
    float* PB  = XQ + (long)B_ * NB;                      // 64*128*4
    unsigned int* PK2 = (unsigned int*)(PB + (long)B_ * NB * 4);   // 2*150*1800
    unsigned int* FLG = PK2 + 2 * 150 * PK_STRIDE;        // 2 * 64*128

    hipFuncSetAttribute(reinterpret_cast<const void*>(scan2),
                        hipFuncAttributeMaxDynamicSharedMemorySize, 80000);
    hipMemsetAsync(FLG, 0, 2 * (size_t)B_ * NB * sizeof(unsigned int), stream);

    copy_feat<<<dim3((B_ * NB * E_) / 1024), 256, 0, stream>>>(features, out);
    pack2<<<dim3((2 * 150 * PK_STRIDE + 255) / 256), 256, 0, stream>>>(gc_whh, gp_wih, PK2);

    // H0 = relu(features @ fc1_w + fc1_b) -> out cols [0,300)
    gemm_bias<0><<<dim3(5, 128), 256, 0, stream>>>(
        features, E_, fc1_w, DH, fc1_b, out, OUTD, B_ * NB, DH, E_, 1);

    for (int l = 0; l < 2; ++l) {
        const float* Hl = out + l * DH;
        gemm_bias<1><<<dim3(15, 128), 256, 0, stream>>>(
            Hl, OUTD, gc_wih + (long)l * G3 * DH, DH, gc_bih + l * G3, GIC, G3, B_ * NB, G3, DH, 0);
        gemm_bias<1><<<dim3(15, 128), 256, 0, stream>>>(
            Hl, OUTD, gp_whh + (long)l * G3 * DH, DH, gp_bhh + l * G3, GHP, G3, B_ * NB, G3, DH, 0);
        xq_kernel<<<dim3(B_ * NB / 4), 256, 0, stream>>>(Hl, gat_w + l * 2 * DH, XQ);
        scan2<<<dim3(SLICES * B_), 512, 77824, stream>>>(
            out, GIC, GHP, XQ, PK2 + (long)l * 150 * PK_STRIDE,
            gc_bhh + l * G3, gp_bih + l * G3, adj,
            gat_w + l * 2 * DH + DH, gat_b + l, PB, FLG + (long)l * B_ * NB, l);
    }
}

// Round 3
// 2408.853 us; speedup vs baseline: 1.6244x; 1.0743x over previous
//
#include <hip/hip_runtime.h>
#include <hip/hip_fp16.h>

#define B_   64
#define NB   128
#define E_   1024
#define DH   300
#define G3   900
#define OUTD 1924
#define SLICES 4
#define SLICE_D 75
#define ROWS_PB 450   // 6*75 weight rows per slice block
#define PK_STRIDE 1800

typedef _Float16 h2raw __attribute__((ext_vector_type(2)));

__device__ __forceinline__ float dot2f(unsigned int m2, unsigned int w, float acc) {
    h2raw a, b;
    __builtin_memcpy(&a, &m2, 4);
    __builtin_memcpy(&b, &w, 4);
    return __builtin_amdgcn_fdot2(a, b, acc, false);
}

__device__ __forceinline__ float sigmoidf_(float x) { return 1.f / (1.f + __expf(-x)); }
__device__ __forceinline__ float tanh_fast(float x) { return 1.f - 2.f / (__expf(2.f * x) + 1.f); }

// ---------------- copy features into output tail ----------------
__global__ __launch_bounds__(256)
void copy_feat(const float* __restrict__ f, float* __restrict__ out) {
    const long id = (long)blockIdx.x * 256 + threadIdx.x;   // one float4 each
    const long r = id >> 8;          // row (b*128+n), 256 float4 per row
    const int  c = (int)(id & 255);
    const float4 v = ((const float4*)(f + r * E_))[c];
    ((float4*)(out + r * OUTD + 3 * DH))[c] = v;
}

// ---------------- pack recurrent weights -> PK2[l][kp(150)][R(1800)] f16-pairs ----------------
__global__ __launch_bounds__(256)
void pack2(const float* __restrict__ gc_whh, const float* __restrict__ gp_wih,
           unsigned int* __restrict__ dst) {
    const int id = blockIdx.x * 256 + threadIdx.x;
    if (id >= 2 * 150 * PK_STRIDE) return;
    const int l   = id / (150 * PK_STRIDE);
    const int rem = id % (150 * PK_STRIDE);
    const int kp  = rem / PK_STRIDE;
    const int R   = rem % PK_STRIDE;
    const int mat = R / G3;
    const int o   = R % G3;
    const float* W = (mat ? gp_wih : gc_whh) + (long)l * G3 * DH;
    const float2 v = *(const float2*)(W + (long)o * DH + 2 * kp);
    __half2 h;
    h.x = __float2half_rn(v.x);
    h.y = __float2half_rn(v.y);
    unsigned int u;
    __builtin_memcpy(&u, &h, 4);
    dst[id] = u;
}

// ---------------- fp32 tiled GEMM ----------------
template<int BLAYOUT>
__global__ __launch_bounds__(256)
void gemm_bias(const float* __restrict__ A, int lda,
               const float* __restrict__ Bm, int ldb,
               const float* __restrict__ bias,
               float* __restrict__ C, int ldc,
               int M, int Nn, int K, int do_relu)
{
    __shared__ float As[16][64];
    __shared__ float Bs[16][64];
    const int tid = threadIdx.x;
    const int m0 = blockIdx.y * 64;
    const int n0 = blockIdx.x * 64;
    const int tx = tid & 15, ty = tid >> 4;
    const int ar = tid >> 2, ak = (tid & 3) << 2;
    const int bk0 = tid >> 4, bn0 = (tid & 15) << 2;
    const int bn1 = tid >> 2, bk1 = (tid & 3) << 2;

    float acc[4][4] = {{0.f}};

    for (int k0 = 0; k0 < K; k0 += 16) {
        {
            const int gr = m0 + ar;
            const int gk = k0 + ak;
            const float* ap = A + (long)gr * lda + gk;
            float v0, v1, v2, v3;
            if (gk + 3 < K) { float4 v = *(const float4*)ap; v0 = v.x; v1 = v.y; v2 = v.z; v3 = v.w; }
            else {
                v0 = (gk + 0 < K) ? ap[0] : 0.f;
                v1 = (gk + 1 < K) ? ap[1] : 0.f;
                v2 = (gk + 2 < K) ? ap[2] : 0.f;
                v3 = (gk + 3 < K) ? ap[3] : 0.f;
            }
            As[ak + 0][ar] = v0; As[ak + 1][ar] = v1; As[ak + 2][ar] = v2; As[ak + 3][ar] = v3;
        }
        if (BLAYOUT == 0) {
            const int gk = k0 + bk0;
            const int gn = n0 + bn0;
            const float* bp = Bm + (long)gk * ldb + gn;
            float4 v;
            if (gk < K && gn + 3 < Nn) v = *(const float4*)bp;
            else {
                v.x = (gk < K && gn + 0 < Nn) ? bp[0] : 0.f;
                v.y = (gk < K && gn + 1 < Nn) ? bp[1] : 0.f;
                v.z = (gk < K && gn + 2 < Nn) ? bp[2] : 0.f;
                v.w = (gk < K && gn + 3 < Nn) ? bp[3] : 0.f;
            }
            *(float4*)&Bs[bk0][bn0] = v;
        } else {
            const int gn = n0 + bn1;
            const int gk = k0 + bk1;
            const float* bp = Bm + (long)gn * ldb + gk;
            float v0, v1, v2, v3;
            if (gn < Nn && gk + 3 < K) { float4 v = *(const float4*)bp; v0 = v.x; v1 = v.y; v2 = v.z; v3 = v.w; }
            else {
                v0 = (gn < Nn && gk + 0 < K) ? bp[0] : 0.f;
                v1 = (gn < Nn && gk + 1 < K) ? bp[1] : 0.f;
                v2 = (gn < Nn && gk + 2 < K) ? bp[2] : 0.f;
                v3 = (gn < Nn && gk + 3 < K) ? bp[3] : 0.f;
            }
            Bs[bk1 + 0][bn1] = v0; Bs[bk1 + 1][bn1] = v1; Bs[bk1 + 2][bn1] = v2; Bs[bk1 + 3][bn1] = v3;
        }
        __syncthreads();
        #pragma unroll
        for (int kk = 0; kk < 16; ++kk) {
            const float4 a4 = *(const float4*)&As[kk][ty << 2];
            const float4 b4 = *(const float4*)&Bs[kk][tx << 2];
            const float a[4] = {a4.x, a4.y, a4.z, a4.w};
            const float b[4] = {b4.x, b4.y, b4.z, b4.w};
            #pragma unroll
            for (int ii = 0; ii < 4; ++ii)
                #pragma unroll
                for (int jj = 0; jj < 4; ++jj)
                    acc[ii][jj] += a[ii] * b[jj];
        }
        __syncthreads();
    }
    const int gn0 = n0 + (tx << 2);
    #pragma unroll
    for (int ii = 0; ii < 4; ++ii) {
        const int gm = m0 + (ty << 2) + ii;
        if (gm >= M) continue;
        if (gn0 + 3 < Nn) {
            const float4 bb = *(const float4*)&bias[gn0];
            float4 o;
            o.x = acc[ii][0] + bb.x; o.y = acc[ii][1] + bb.y;
            o.z = acc[ii][2] + bb.z; o.w = acc[ii][3] + bb.w;
            if (do_relu) { o.x = fmaxf(o.x, 0.f); o.y = fmaxf(o.y, 0.f); o.z = fmaxf(o.z, 0.f); o.w = fmaxf(o.w, 0.f); }
            *(float4*)&C[(long)gm * ldc + gn0] = o;
        } else if (gn0 < Nn) {
            for (int jj = 0; jj < 4; ++jj) {
                const int gn = gn0 + jj;
                if (gn < Nn) {
                    float v = acc[ii][jj] + bias[gn];
                    if (do_relu) v = fmaxf(v, 0.f);
                    C[(long)gm * ldc + gn] = v;
                }
            }
        }
    }
}

// ---------------- xq[r] = Hl[r,:] . wq ----------------
__global__ __launch_bounds__(256)
void xq_kernel(const float* __restrict__ H, const float* __restrict__ wq, float* __restrict__ XQ) {
    const int lane = threadIdx.x & 63;
    const int wid = threadIdx.x >> 6;
    const long r = (long)blockIdx.x * 4 + wid;
    const float* h = H + r * OUTD;
    float s = 0.f;
    for (int d = lane; d < DH; d += 64) s += h[d] * wq[d];
    #pragma unroll
    for (int off = 32; off; off >>= 1) s += __shfl_xor(s, off);
    if (lane == 0) XQ[r] = s;
}

// ---------------- DAG scan v3: payload-packed release/acquire handoff ----------------
// TB word per (b, i, slice): { beta_partial f32 (hi32) | tag = i+1 (lo32) }
__global__ __launch_bounds__(512, 2)
void scan3(float* __restrict__ out,
           const float* __restrict__ GIC,
           const float* __restrict__ GHP,
           const float* __restrict__ XQ,
           const unsigned int* __restrict__ PK2L,
           const float* __restrict__ cbhh,
           const float* __restrict__ pbih,
           const int* __restrict__ adj,
           const float* __restrict__ wk,
           const float* __restrict__ gatb,
           unsigned long long* __restrict__ TB,
           int l)
{
    extern __shared__ unsigned int histp[];   // [128][152] f16-pairs
    __shared__ float wsm[NB];
    __shared__ float betas[NB];
    __shared__ float xqs[NB];
    __shared__ float Mlds[DH];
    __shared__ __align__(16) unsigned int M2[152];
    __shared__ float gmv[ROWS_PB];
    __shared__ float red[8];
    __shared__ float red2[8];
    __shared__ float betaown;

    const int tid = threadIdx.x;
    const int lane = tid & 63;
    const int wid = tid >> 6;
    const int b = blockIdx.x & 63;
    const int k = blockIdx.x >> 6;

    const float bg = *gatb;
    float* outb = out + (long)b * NB * OUTD;
    const float* xcol = outb + l * DH;
    float* ycol = outb + (l + 1) * DH;
    const float* gicb = GIC + (long)b * NB * G3;
    const float* ghpb = GHP + (long)b * NB * G3;
    const int* adjb = adj + b * NB * NB;
    unsigned long long* tb = TB + (long)b * NB * SLICES;

    if (tid < NB) xqs[tid] = XQ[b * NB + tid];
    if (tid < 152) M2[tid] = 0u;
    if (tid == 0) betaown = 0.f;

    // loop-invariant per-dim constants (tid < 75 meaningful)
    const int D = k * SLICE_D + ((tid < SLICE_D) ? tid : 0);
    const float cb0 = cbhh[D], cb1 = cbhh[DH + D], cb2 = cbhh[2 * DH + D];
    const float pb0 = pbih[D], pb1 = pbih[DH + D], pb2 = pbih[2 * DH + D];
    const float wkD = wk[D];

    // this slice's weight rows into registers
    int R;
    {
        const int t = (tid < ROWS_PB) ? tid : 0;
        const int d = t % SLICE_D;
        const int r = t / SLICE_D;            // 0..5 = (mat, gate)
        const int mat = r / 3, gate = r % 3;
        R = mat * G3 + gate * DH + k * SLICE_D + d;
    }
    unsigned int w[152];
    #pragma unroll
    for (int j = 0; j < 150; ++j) w[j] = PK2L[j * PK_STRIDE + R];
    w[150] = 0u; w[151] = 0u;

    __syncthreads();

    for (int i = 0; i < NB; ++i) {
        // ---- prefetch pure inputs (no ordering needed; hides under the poll) ----
        int adjn = 0;
        if (tid < NB) adjn = adjb[i * NB + tid];
        float gi0 = 0, gi1 = 0, gi2 = 0, gp0 = 0, gp1 = 0, gp2 = 0, xi = 0;
        if (tid < SLICE_D) {
            const float* gic = gicb + (long)i * G3;
            const float* ghp = ghpb + (long)i * G3;
            gi0 = gic[D]; gi1 = gic[DH + D]; gi2 = gic[2 * DH + D];
            gp0 = ghp[D]; gp1 = ghp[DH + D]; gp2 = ghp[2 * DH + D];
            xi = xcol[(long)i * OUTD + D];
        }

        if (i > 0) {
            // ---- wave0: poll 3 remote slice packets of row i-1, combine betas ----
            if (wid == 0) {
                const bool act = (lane < SLICES) && (lane != k);
                unsigned long long tv = 0;
                if (act) tv = __hip_atomic_load(&tb[(i - 1) * SLICES + lane],
                                                __ATOMIC_RELAXED, __HIP_MEMORY_SCOPE_AGENT);
                while (!__all(!act || (unsigned int)tv == (unsigned int)i)) {
                    __builtin_amdgcn_s_sleep(1);
                    if (act && (unsigned int)tv != (unsigned int)i)
                        tv = __hip_atomic_load(&tb[(i - 1) * SLICES + lane],
                                               __ATOMIC_RELAXED, __HIP_MEMORY_SCOPE_AGENT);
                }
                if (lane == 0)
                    (void)__hip_atomic_load(&tb[(i - 1) * SLICES + ((k + 1) & 3)],
                                            __ATOMIC_ACQUIRE, __HIP_MEMORY_SCOPE_AGENT);
                float bp = 0.f;
                if (lane < SLICES) {
                    if (lane == k) bp = betaown;
                    else {
                        const unsigned int hi = (unsigned int)(tv >> 32);
                        __builtin_memcpy(&bp, &hi, 4);
                    }
                }
                bp += __shfl_xor(bp, 1);
                bp += __shfl_xor(bp, 2);
                if (lane == 0) betas[i - 1] = bp;
            }
            __syncthreads();   // B1: acquire + betas[i-1] visible to all

            // ---- ingest row i-1 (post-acquire) + softmax max, overlapped ----
            float2 yv = make_float2(0.f, 0.f);
            if (tid < 150) yv = *(const float2*)(ycol + (long)(i - 1) * OUTD + 2 * tid);

            float aj = -3.0e38f;
            bool valid = false;
            if (tid < i) {
                valid = (adjn != 0);
                if (valid) aj = xqs[i] + bg + betas[tid];
            }
            float mx = aj;
            #pragma unroll
            for (int off = 32; off; off >>= 1) mx = fmaxf(mx, __shfl_xor(mx, off));
            if (lane == 0) red[wid] = mx;

            if (tid < 150) {
                __half2 h;
                h.x = __float2half_rn(yv.x);
                h.y = __float2half_rn(yv.y);
                unsigned int u;
                __builtin_memcpy(&u, &h, 4);
                histp[(i - 1) * 152 + tid] = u;
            }
            __syncthreads();   // B2

            const float amax = fmaxf(red[0], red[1]);
            const float e = valid ? __expf(aj - amax) : 0.f;
            if (tid < NB) wsm[tid] = e;     // unnormalized
            float s = e;
            #pragma unroll
            for (int off = 32; off; off >>= 1) s += __shfl_xor(s, off);
            if (lane == 0) red2[wid] = s;
            __syncthreads();   // B3

            const float inv = 1.f / (red2[0] + red2[1]);
            if (tid < 150) {
                float m0 = 0.f, m1 = 0.f;
                #pragma unroll 4
                for (int j = 0; j < i; ++j) {
                    const unsigned int u = histp[j * 152 + tid];
                    __half2 h;
                    __builtin_memcpy(&h, &u, 4);
                    const float wj = wsm[j];
                    m0 = fmaf(wj, __half2float(h.x), m0);
                    m1 = fmaf(wj, __half2float(h.y), m1);
                }
                m0 *= inv; m1 *= inv;
                Mlds[2 * tid] = m0;
                Mlds[2 * tid + 1] = m1;
                __half2 h;
                h.x = __float2half_rn(m0);
                h.y = __float2half_rn(m1);
                unsigned int u;
                __builtin_memcpy(&u, &h, 4);
                M2[tid] = u;
            }
        } else {
            if (tid < DH) Mlds[tid] = 0.f;   // M2 pre-zeroed
        }
        __syncthreads();   // B4: M ready

        // ---- matvec from register weights ----
        if (tid < ROWS_PB) {
            float a0 = 0.f, a1 = 0.f;
            #pragma unroll
            for (int j4 = 0; j4 < 152; j4 += 4) {
                const uint4 m4 = *(const uint4*)&M2[j4];
                a0 = dot2f(m4.x, w[j4 + 0], a0);
                a1 = dot2f(m4.y, w[j4 + 1], a1);
                a0 = dot2f(m4.z, w[j4 + 2], a0);
                a1 = dot2f(m4.w, w[j4 + 3], a1);
            }
            gmv[tid] = a0 + a1;
        }
        __syncthreads();   // B5: gmv ready

        // ---- gates ----
        float bv = 0.f;
        if (tid < SLICE_D) {
            const float Mi = Mlds[D];
            const float hc0 = gmv[0 * SLICE_D + tid] + cb0;
            const float hc1 = gmv[1 * SLICE_D + tid] + cb1;
            const float hc2 = gmv[2 * SLICE_D + tid] + cb2;
            const float rc = sigmoidf_(gi0 + hc0);
            const float zc = sigmoidf_(gi1 + hc1);
            const float nc = tanh_fast(gi2 + rc * hc2);
            const float Cc = (1.f - zc) * nc + zc * Mi;
            const float ip0 = gmv[3 * SLICE_D + tid] + pb0;
            const float ip1 = gmv[4 * SLICE_D + tid] + pb1;
            const float ip2 = gmv[5 * SLICE_D + tid] + pb2;
            const float rp = sigmoidf_(ip0 + gp0);
            const float zp = sigmoidf_(ip1 + gp1);
            const float np = tanh_fast(ip2 + rp * gp2);
            const float Pp = (1.f - zp) * np + zp * xi;
            const float rowv = Cc + Pp;
            ycol[(long)i * OUTD + D] = rowv;
            bv = rowv * wkD;
        }
        #pragma unroll
        for (int off = 32; off; off >>= 1) bv += __shfl_xor(bv, off);
        if (lane == 0) red[wid] = bv;
        __syncthreads();   // B6: ycol stores drained (vmcnt0 at barrier), partials in red

        if (tid == 0) {
            const float bsum = red[0] + red[1];
            betaown = bsum;
            unsigned int bbits;
            __builtin_memcpy(&bbits, &bsum, 4);
            const unsigned long long pkt =
                ((unsigned long long)bbits << 32) | (unsigned int)(i + 1);
            __hip_atomic_store(&tb[i * SLICES + k], pkt,
                               __ATOMIC_RELEASE, __HIP_MEMORY_SCOPE_AGENT);
        }
    }
}

extern "C" void kernel_launch(void* const* d_in, const int* in_sizes, int n_in,
                              void* d_out, int out_size, void* d_ws, size_t ws_size,
                              hipStream_t stream) {
    (void)in_sizes; (void)n_in; (void)out_size; (void)ws_size;
    const float* features = (const float*)d_in[0];
    const float* fc1_w    = (const float*)d_in[1];
    const float* fc1_b    = (const float*)d_in[2];
    const float* gat_w    = (const float*)d_in[3];
    const float* gat_b    = (const float*)d_in[4];
    const float* gc_wih   = (const float*)d_in[5];
    const float* gc_whh   = (const float*)d_in[6];
    const float* gc_bih   = (const float*)d_in[7];
    const float* gc_bhh   = (const float*)d_in[8];
    const float* gp_wih   = (const float*)d_in[9];
    const float* gp_whh   = (const float*)d_in[10];
    const float* gp_bih   = (const float*)d_in[11];
    const float* gp_bhh   = (const float*)d_in[12];
    const int*   adj      = (const int*)d_in[13];
    float* out = (float*)d_out;

    unsigned long long* TB = (unsigned long long*)d_ws;       // 2 * 64*128*4 packets
    float* GIC = (float*)(TB + 2L * B_ * NB * SLICES);        // 64*128*900
    float* GHP = GIC + (long)B_ * NB * G3;                    // 64*128*900
    float* XQ  = GHP + (long)B_ * NB * G3;                    // 8192
    unsigned int* PK2 = (unsigned int*)(XQ + (long)B_ * NB);  // 2*150*1800

    hipFuncSetAttribute(reinterpret_cast<const void*>(scan3),
                        hipFuncAttributeMaxDynamicSharedMemorySize, 80000);
    hipMemsetAsync(TB, 0, 2L * B_ * NB * SLICES * sizeof(unsigned long long), stream);

    copy_feat<<<dim3((B_ * NB * E_) / 1024), 256, 0, stream>>>(features, out);
    pack2<<<dim3((2 * 150 * PK_STRIDE + 255) / 256), 256, 0, stream>>>(gc_whh, gp_wih, PK2);

    gemm_bias<0><<<dim3(5, 128), 256, 0, stream>>>(
        features, E_, fc1_w, DH, fc1_b, out, OUTD, B_ * NB, DH, E_, 1);

    for (int l = 0; l < 2; ++l) {
        const float* Hl = out + l * DH;
        gemm_bias<1><<<dim3(15, 128), 256, 0, stream>>>(
            Hl, OUTD, gc_wih + (long)l * G3 * DH, DH, gc_bih + l * G3, GIC, G3, B_ * NB, G3, DH, 0);
        gemm_bias<1><<<dim3(15, 128), 256, 0, stream>>>(
            Hl, OUTD, gp_whh + (long)l * G3 * DH, DH, gp_bhh + l * G3, GHP, G3, B_ * NB, G3, DH, 0);
        xq_kernel<<<dim3(B_ * NB / 4), 256, 0, stream>>>(Hl, gat_w + l * 2 * DH, XQ);
        scan3<<<dim3(SLICES * B_), 512, 77824, stream>>>(
            out, GIC, GHP, XQ, PK2 + (long)l * 150 * PK_STRIDE,
            gc_bhh + l * G3, gp_bih + l * G3, adj,
            gat_w + l * 2 * DH + DH, gat_b + l,
            TB + (long)l * B_ * NB * SLICES, l);
    }
}

// Round 4
// 1605.745 us; speedup vs baseline: 2.4368x; 1.5001x over previous
//
#include <hip/hip_runtime.h>
#include <hip/hip_fp16.h>

#define B_   64
#define NB   128
#define E_   1024
#define DH   300
#define G3   900
#define OUTD 1924
#define SLICES 4
#define PK_STRIDE 1800
#define MSG_U64 80          // per (b,i): 75 u64 data (150 f16-pair words) + pad + 4 tag u64

typedef _Float16 h2raw __attribute__((ext_vector_type(2)));

__device__ __forceinline__ float dot2f(unsigned int m2, unsigned int w, float acc) {
    h2raw a, b;
    __builtin_memcpy(&a, &m2, 4);
    __builtin_memcpy(&b, &w, 4);
    return __builtin_amdgcn_fdot2(a, b, acc, false);
}

__device__ __forceinline__ float sigmoidf_(float x) { return 1.f / (1.f + __expf(-x)); }
__device__ __forceinline__ float tanh_fast(float x) { return 1.f - 2.f / (__expf(2.f * x) + 1.f); }

// ---------------- copy features into output tail ----------------
__global__ __launch_bounds__(256)
void copy_feat(const float* __restrict__ f, float* __restrict__ out) {
    const long id = (long)blockIdx.x * 256 + threadIdx.x;
    const long r = id >> 8;
    const int  c = (int)(id & 255);
    const float4 v = ((const float4*)(f + r * E_))[c];
    ((float4*)(out + r * OUTD + 3 * DH))[c] = v;
}

// ---------------- pack recurrent weights -> PK2[l][kp(150)][R(1800)] f16-pairs ----------------
__global__ __launch_bounds__(256)
void pack2(const float* __restrict__ gc_whh, const float* __restrict__ gp_wih,
           unsigned int* __restrict__ dst) {
    const int id = blockIdx.x * 256 + threadIdx.x;
    if (id >= 2 * 150 * PK_STRIDE) return;
    const int l   = id / (150 * PK_STRIDE);
    const int rem = id % (150 * PK_STRIDE);
    const int kp  = rem / PK_STRIDE;
    const int R   = rem % PK_STRIDE;
    const int mat = R / G3;
    const int o   = R % G3;
    const float* W = (mat ? gp_wih : gc_whh) + (long)l * G3 * DH;
    const float2 v = *(const float2*)(W + (long)o * DH + 2 * kp);
    __half2 h;
    h.x = __float2half_rn(v.x);
    h.y = __float2half_rn(v.y);
    unsigned int u;
    __builtin_memcpy(&u, &h, 4);
    dst[id] = u;
}

// ---------------- fp32 tiled GEMM ----------------
template<int BLAYOUT>
__global__ __launch_bounds__(256)
void gemm_bias(const float* __restrict__ A, int lda,
               const float* __restrict__ Bm, int ldb,
               const float* __restrict__ bias,
               float* __restrict__ C, int ldc,
               int M, int Nn, int K, int do_relu)
{
    __shared__ float As[16][64];
    __shared__ float Bs[16][64];
    const int tid = threadIdx.x;
    const int m0 = blockIdx.y * 64;
    const int n0 = blockIdx.x * 64;
    const int tx = tid & 15, ty = tid >> 4;
    const int ar = tid >> 2, ak = (tid & 3) << 2;
    const int bk0 = tid >> 4, bn0 = (tid & 15) << 2;
    const int bn1 = tid >> 2, bk1 = (tid & 3) << 2;

    float acc[4][4] = {{0.f}};

    for (int k0 = 0; k0 < K; k0 += 16) {
        {
            const int gr = m0 + ar;
            const int gk = k0 + ak;
            const float* ap = A + (long)gr * lda + gk;
            float v0, v1, v2, v3;
            if (gk + 3 < K) { float4 v = *(const float4*)ap; v0 = v.x; v1 = v.y; v2 = v.z; v3 = v.w; }
            else {
                v0 = (gk + 0 < K) ? ap[0] : 0.f;
                v1 = (gk + 1 < K) ? ap[1] : 0.f;
                v2 = (gk + 2 < K) ? ap[2] : 0.f;
                v3 = (gk + 3 < K) ? ap[3] : 0.f;
            }
            As[ak + 0][ar] = v0; As[ak + 1][ar] = v1; As[ak + 2][ar] = v2; As[ak + 3][ar] = v3;
        }
        if (BLAYOUT == 0) {
            const int gk = k0 + bk0;
            const int gn = n0 + bn0;
            const float* bp = Bm + (long)gk * ldb + gn;
            float4 v;
            if (gk < K && gn + 3 < Nn) v = *(const float4*)bp;
            else {
                v.x = (gk < K && gn + 0 < Nn) ? bp[0] : 0.f;
                v.y = (gk < K && gn + 1 < Nn) ? bp[1] : 0.f;
                v.z = (gk < K && gn + 2 < Nn) ? bp[2] : 0.f;
                v.w = (gk < K && gn + 3 < Nn) ? bp[3] : 0.f;
            }
            *(float4*)&Bs[bk0][bn0] = v;
        } else {
            const int gn = n0 + bn1;
            const int gk = k0 + bk1;
            const float* bp = Bm + (long)gn * ldb + gk;
            float v0, v1, v2, v3;
            if (gn < Nn && gk + 3 < K) { float4 v = *(const float4*)bp; v0 = v.x; v1 = v.y; v2 = v.z; v3 = v.w; }
            else {
                v0 = (gn < Nn && gk + 0 < K) ? bp[0] : 0.f;
                v1 = (gn < Nn && gk + 1 < K) ? bp[1] : 0.f;
                v2 = (gn < Nn && gk + 2 < K) ? bp[2] : 0.f;
                v3 = (gn < Nn && gk + 3 < K) ? bp[3] : 0.f;
            }
            Bs[bk1 + 0][bn1] = v0; Bs[bk1 + 1][bn1] = v1; Bs[bk1 + 2][bn1] = v2; Bs[bk1 + 3][bn1] = v3;
        }
        __syncthreads();
        #pragma unroll
        for (int kk = 0; kk < 16; ++kk) {
            const float4 a4 = *(const float4*)&As[kk][ty << 2];
            const float4 b4 = *(const float4*)&Bs[kk][tx << 2];
            const float a[4] = {a4.x, a4.y, a4.z, a4.w};
            const float b[4] = {b4.x, b4.y, b4.z, b4.w};
            #pragma unroll
            for (int ii = 0; ii < 4; ++ii)
                #pragma unroll
                for (int jj = 0; jj < 4; ++jj)
                    acc[ii][jj] += a[ii] * b[jj];
        }
        __syncthreads();
    }
    const int gn0 = n0 + (tx << 2);
    #pragma unroll
    for (int ii = 0; ii < 4; ++ii) {
        const int gm = m0 + (ty << 2) + ii;
        if (gm >= M) continue;
        if (gn0 + 3 < Nn) {
            const float4 bb = *(const float4*)&bias[gn0];
            float4 o;
            o.x = acc[ii][0] + bb.x; o.y = acc[ii][1] + bb.y;
            o.z = acc[ii][2] + bb.z; o.w = acc[ii][3] + bb.w;
            if (do_relu) { o.x = fmaxf(o.x, 0.f); o.y = fmaxf(o.y, 0.f); o.z = fmaxf(o.z, 0.f); o.w = fmaxf(o.w, 0.f); }
            *(float4*)&C[(long)gm * ldc + gn0] = o;
        } else if (gn0 < Nn) {
            for (int jj = 0; jj < 4; ++jj) {
                const int gn = gn0 + jj;
                if (gn < Nn) {
                    float v = acc[ii][jj] + bias[gn];
                    if (do_relu) v = fmaxf(v, 0.f);
                    C[(long)gm * ldc + gn] = v;
                }
            }
        }
    }
}

// ---------------- xq[r] = Hl[r,:] . wq ----------------
__global__ __launch_bounds__(256)
void xq_kernel(const float* __restrict__ H, const float* __restrict__ wq, float* __restrict__ XQ) {
    const int lane = threadIdx.x & 63;
    const int wid = threadIdx.x >> 6;
    const long r = (long)blockIdx.x * 4 + wid;
    const float* h = H + r * OUTD;
    float s = 0.f;
    for (int d = lane; d < DH; d += 64) s += h[d] * wq[d];
    #pragma unroll
    for (int off = 32; off; off >>= 1) s += __shfl_xor(s, off);
    if (lane == 0) XQ[r] = s;
}

// ---------------- DAG scan v4: L2-bypassing relaxed-atomic mailbox, no acquire/release ----------------
// Mailbox per (b,i): u64[80] = { data u64 0..74 (150 f16-pair words, kp-indexed),
//                                pad u64 75, tags u64 76..79 = {beta_partial|i+1} per slice }
// Slices are pair-aligned: dims [76k, 76k+sw), sw = 76,76,76,72.
__global__ __launch_bounds__(512, 2)
void scan4(float* __restrict__ out,
           const float* __restrict__ GIC,
           const float* __restrict__ GHP,
           const float* __restrict__ XQ,
           const unsigned int* __restrict__ PK2L,
           const float* __restrict__ cbhh,
           const float* __restrict__ pbih,
           const int* __restrict__ adj,
           const float* __restrict__ wk,
           const float* __restrict__ gatb,
           unsigned long long* __restrict__ TBL,   // layer base: [64][128][MSG_U64]
           int l)
{
    extern __shared__ unsigned int histp[];   // [128][152] f16-pairs, kp-indexed
    __shared__ float wsm[NB];
    __shared__ float betas[NB];
    __shared__ float xqs[NB];
    __shared__ float Mlds[DH];
    __shared__ __align__(16) unsigned int M2[152];
    __shared__ float gmv[456];
    __shared__ float red[8];

    const int tid = threadIdx.x;
    const int lane = tid & 63;
    const int wid = tid >> 6;
    const int b = blockIdx.x & 63;
    const int k = blockIdx.x >> 6;
    const int swk = (k == 3) ? 72 : 76;
    const int ROWS = 6 * swk;

    const float bg = *gatb;
    float* outb = out + (long)b * NB * OUTD;
    const float* xcol = outb + l * DH;
    float* ycol = outb + (l + 1) * DH;
    const float* gicb = GIC + (long)b * NB * G3;
    const float* ghpb = GHP + (long)b * NB * G3;
    const int* adjb = adj + b * NB * NB;
    unsigned long long* tbu64 = TBL + (long)b * NB * MSG_U64;
    unsigned int* tb32 = (unsigned int*)tbu64;

    if (tid < NB) xqs[tid] = XQ[b * NB + tid];
    if (tid < 152) M2[tid] = 0u;

    // per-dim loop invariants (valid for tid < swk)
    const int D = 76 * k + ((tid < swk) ? tid : 0);
    const float cb0 = cbhh[D], cb1 = cbhh[DH + D], cb2 = cbhh[2 * DH + D];
    const float pb0 = pbih[D], pb1 = pbih[DH + D], pb2 = pbih[2 * DH + D];
    const float wkD = wk[D];

    // this slice's weight rows into registers (row r = mat*3+gate local, dim d)
    int R;
    {
        const int t = (tid < ROWS) ? tid : 0;
        const int d = t % swk;
        const int r = t / swk;
        R = (r / 3) * G3 + (r % 3) * DH + 76 * k + d;
    }
    unsigned int w[152];
    #pragma unroll
    for (int j = 0; j < 150; ++j) w[j] = PK2L[j * PK_STRIDE + R];
    w[150] = 0u; w[151] = 0u;

    __syncthreads();

    for (int i = 0; i < NB; ++i) {
        // ---- prefetch pure inputs (overlap with poll) ----
        int adj0 = 0, adj1 = 0;
        if (wid == 0 && i > 0) {
            adj0 = adjb[i * NB + lane];
            adj1 = adjb[i * NB + 64 + lane];
        }
        float gi0 = 0, gi1 = 0, gi2 = 0, gp0 = 0, gp1 = 0, gp2 = 0, xi = 0;
        if (tid < swk) {
            const float* gic = gicb + (long)i * G3;
            const float* ghp = ghpb + (long)i * G3;
            gi0 = gic[D]; gi1 = gic[DH + D]; gi2 = gic[2 * DH + D];
            gp0 = ghp[D]; gp1 = ghp[DH + D]; gp2 = ghp[2 * DH + D];
            xi = xcol[(long)i * OUTD + D];
        }

        if (i > 0) {
            if (wid == 0) {
                const unsigned long long* trow = tbu64 + (long)(i - 1) * MSG_U64;
                // ---- poll the 4 slice tags of row i-1 (relaxed, L2-bypassing) ----
                const bool act = (lane < SLICES);
                unsigned long long tv = 0;
                while (true) {
                    if (act && (unsigned int)tv != (unsigned int)i)
                        tv = __hip_atomic_load(&trow[76 + lane],
                                               __ATOMIC_RELAXED, __HIP_MEMORY_SCOPE_AGENT);
                    if (__all(!act || (unsigned int)tv == (unsigned int)i)) break;
                }
                // ---- combine beta partials ----
                float bp = 0.f;
                if (act) {
                    const unsigned int hi = (unsigned int)(tv >> 32);
                    __builtin_memcpy(&bp, &hi, 4);
                }
                bp += __shfl_xor(bp, 1);
                bp += __shfl_xor(bp, 2);
                const float beta_new = __shfl(bp, 0);
                if (lane == 0) betas[i - 1] = beta_new;

                // ---- issue y-row data loads (latency hides under softmax) ----
                unsigned long long d0 = 0, d1 = 0;
                if (lane < 38) {
                    d0 = __hip_atomic_load(&trow[2 * lane],
                                           __ATOMIC_RELAXED, __HIP_MEMORY_SCOPE_AGENT);
                    d1 = __hip_atomic_load(&trow[2 * lane + 1],
                                           __ATOMIC_RELAXED, __HIP_MEMORY_SCOPE_AGENT);
                }

                // ---- wave0-only softmax over j < i (2 j's per lane) ----
                const float base = xqs[i] + bg;
                const int j1 = lane + 64;
                const bool v0 = (lane < i) && (adj0 != 0);
                const bool v1 = (j1 < i) && (adj1 != 0);
                const float bb0 = (lane == i - 1) ? beta_new : betas[lane];
                const float bb1 = (j1 == i - 1) ? beta_new : betas[j1 & (NB - 1)];
                float a0 = v0 ? base + bb0 : -3.0e38f;
                float a1 = v1 ? base + bb1 : -3.0e38f;
                float mx = fmaxf(a0, a1);
                #pragma unroll
                for (int off = 32; off; off >>= 1) mx = fmaxf(mx, __shfl_xor(mx, off));
                const float e0 = v0 ? __expf(a0 - mx) : 0.f;
                const float e1 = v1 ? __expf(a1 - mx) : 0.f;
                float s = e0 + e1;
                #pragma unroll
                for (int off = 32; off; off >>= 1) s += __shfl_xor(s, off);
                const float inv = 1.f / s;
                wsm[lane] = e0 * inv;
                wsm[j1]   = e1 * inv;

                // ---- ingest y-row f16 pairs straight into LDS history ----
                if (lane < 38) {
                    uint4 q;
                    q.x = (unsigned int)d0; q.y = (unsigned int)(d0 >> 32);
                    q.z = (unsigned int)d1; q.w = (unsigned int)(d1 >> 32);
                    *(uint4*)&histp[(i - 1) * 152 + 4 * lane] = q;
                }
            }
            __syncthreads();   // B1: betas, wsm, history row i-1 visible

            // ---- M = sum_j wsm_j * y_j (normalized weights) ----
            if (tid < 150) {
                float m0 = 0.f, m1 = 0.f;
                #pragma unroll 4
                for (int j = 0; j < i; ++j) {
                    const unsigned int u = histp[j * 152 + tid];
                    __half2 h;
                    __builtin_memcpy(&h, &u, 4);
                    const float wj = wsm[j];
                    m0 = fmaf(wj, __half2float(h.x), m0);
                    m1 = fmaf(wj, __half2float(h.y), m1);
                }
                Mlds[2 * tid] = m0;
                Mlds[2 * tid + 1] = m1;
                __half2 h;
                h.x = __float2half_rn(m0);
                h.y = __float2half_rn(m1);
                unsigned int u;
                __builtin_memcpy(&u, &h, 4);
                M2[tid] = u;
            }
        } else {
            if (tid < DH) Mlds[tid] = 0.f;   // M2 pre-zeroed at init
        }
        __syncthreads();   // B4: M ready

        // ---- matvec from register weights ----
        if (tid < ROWS) {
            float a0 = 0.f, a1 = 0.f;
            #pragma unroll
            for (int j4 = 0; j4 < 152; j4 += 4) {
                const uint4 m4 = *(const uint4*)&M2[j4];
                a0 = dot2f(m4.x, w[j4 + 0], a0);
                a1 = dot2f(m4.y, w[j4 + 1], a1);
                a0 = dot2f(m4.z, w[j4 + 2], a0);
                a1 = dot2f(m4.w, w[j4 + 3], a1);
            }
            gmv[tid] = a0 + a1;
        }
        __syncthreads();   // B5: gmv ready

        // ---- gates for this slice's dims ----
        float rowv = 0.f;
        if (tid < swk) {
            const float Mi = Mlds[D];
            const float hc0 = gmv[0 * swk + tid] + cb0;
            const float hc1 = gmv[1 * swk + tid] + cb1;
            const float hc2 = gmv[2 * swk + tid] + cb2;
            const float rc = sigmoidf_(gi0 + hc0);
            const float zc = sigmoidf_(gi1 + hc1);
            const float nc = tanh_fast(gi2 + rc * hc2);
            const float Cc = (1.f - zc) * nc + zc * Mi;
            const float ip0 = gmv[3 * swk + tid] + pb0;
            const float ip1 = gmv[4 * swk + tid] + pb1;
            const float ip2 = gmv[5 * swk + tid] + pb2;
            const float rp = sigmoidf_(ip0 + gp0);
            const float zp = sigmoidf_(ip1 + gp1);
            const float np = tanh_fast(ip2 + rp * gp2);
            const float Pp = (1.f - zp) * np + zp * xi;
            rowv = Cc + Pp;
            ycol[(long)i * OUTD + D] = rowv;   // plain store: off critical path
        }

        // ---- ship f16 pairs to the mailbox (relaxed atomic, bypasses L2) ----
        {
            const float part = __shfl_xor(rowv, 1);
            if (tid < swk && !(tid & 1)) {
                __half2 h;
                h.x = __float2half_rn(rowv);
                h.y = __float2half_rn(part);
                unsigned int u;
                __builtin_memcpy(&u, &h, 4);
                __hip_atomic_store(&tb32[(long)i * (MSG_U64 * 2) + 38 * k + (tid >> 1)], u,
                                   __ATOMIC_RELAXED, __HIP_MEMORY_SCOPE_AGENT);
            }
        }

        // ---- beta partial over this slice's dims ----
        float bv = (tid < swk) ? rowv * wkD : 0.f;
        #pragma unroll
        for (int off = 32; off; off >>= 1) bv += __shfl_xor(bv, off);
        if (lane == 0) red[wid] = bv;
        __syncthreads();   // B6: implicit vmcnt(0) drains data stores (acked at coherent point)

        if (tid == 0) {
            const float bsum = red[0] + red[1];
            unsigned int bbits;
            __builtin_memcpy(&bbits, &bsum, 4);
            const unsigned long long pkt =
                ((unsigned long long)bbits << 32) | (unsigned int)(i + 1);
            __hip_atomic_store(&tbu64[(long)i * MSG_U64 + 76 + k], pkt,
                               __ATOMIC_RELAXED, __HIP_MEMORY_SCOPE_AGENT);
        }
    }
}

extern "C" void kernel_launch(void* const* d_in, const int* in_sizes, int n_in,
                              void* d_out, int out_size, void* d_ws, size_t ws_size,
                              hipStream_t stream) {
    (void)in_sizes; (void)n_in; (void)out_size; (void)ws_size;
    const float* features = (const float*)d_in[0];
    const float* fc1_w    = (const float*)d_in[1];
    const float* fc1_b    = (const float*)d_in[2];
    const float* gat_w    = (const float*)d_in[3];
    const float* gat_b    = (const float*)d_in[4];
    const float* gc_wih   = (const float*)d_in[5];
    const float* gc_whh   = (const float*)d_in[6];
    const float* gc_bih   = (const float*)d_in[7];
    const float* gc_bhh   = (const float*)d_in[8];
    const float* gp_wih   = (const float*)d_in[9];
    const float* gp_whh   = (const float*)d_in[10];
    const float* gp_bih   = (const float*)d_in[11];
    const float* gp_bhh   = (const float*)d_in[12];
    const int*   adj      = (const int*)d_in[13];
    float* out = (float*)d_out;

    unsigned long long* TB = (unsigned long long*)d_ws;        // 2 * 64*128*80 u64
    float* GIC = (float*)(TB + 2L * B_ * NB * MSG_U64);        // 64*128*900
    float* GHP = GIC + (long)B_ * NB * G3;                     // 64*128*900
    float* XQ  = GHP + (long)B_ * NB * G3;                     // 8192
    unsigned int* PK2 = (unsigned int*)(XQ + (long)B_ * NB);   // 2*150*1800

    hipFuncSetAttribute(reinterpret_cast<const void*>(scan4),
                        hipFuncAttributeMaxDynamicSharedMemorySize, 80000);
    hipMemsetAsync(TB, 0, 2L * B_ * NB * MSG_U64 * sizeof(unsigned long long), stream);

    copy_feat<<<dim3((B_ * NB * E_) / 1024), 256, 0, stream>>>(features, out);
    pack2<<<dim3((2 * 150 * PK_STRIDE + 255) / 256), 256, 0, stream>>>(gc_whh, gp_wih, PK2);

    gemm_bias<0><<<dim3(5, 128), 256, 0, stream>>>(
        features, E_, fc1_w, DH, fc1_b, out, OUTD, B_ * NB, DH, E_, 1);

    for (int l = 0; l < 2; ++l) {
        const float* Hl = out + l * DH;
        gemm_bias<1><<<dim3(15, 128), 256, 0, stream>>>(
            Hl, OUTD, gc_wih + (long)l * G3 * DH, DH, gc_bih + l * G3, GIC, G3, B_ * NB, G3, DH, 0);
        gemm_bias<1><<<dim3(15, 128), 256, 0, stream>>>(
            Hl, OUTD, gp_whh + (long)l * G3 * DH, DH, gp_bhh + l * G3, GHP, G3, B_ * NB, G3, DH, 0);
        xq_kernel<<<dim3(B_ * NB / 4), 256, 0, stream>>>(Hl, gat_w + l * 2 * DH, XQ);
        scan4<<<dim3(SLICES * B_), 512, 77824, stream>>>(
            out, GIC, GHP, XQ, PK2 + (long)l * 150 * PK_STRIDE,
            gc_bhh + l * G3, gp_bih + l * G3, adj,
            gat_w + l * 2 * DH + DH, gat_b + l,
            TB + (long)l * B_ * NB * MSG_U64, l);
    }
}